// Round 4
// baseline (222.842 us; speedup 1.0000x reference)
//
#include <hip/hip_runtime.h>
#include <math.h>

#define N_IMG 32
#define C_CH  256
#define H     56
#define W     56
#define HW    (H * W)          // 3136
#define CHW   (C_CH * HW)      // 802816
#define HW4   (HW / 4)         // 784
#define W4    (W / 4)          // 14

// ---------------------------------------------------------------------------
// Kernel A: per-(n,h,w) channel mean and max over C=256.
// Block = 256 threads: 8 channel-subgroups x 32 float4-positions.
// Each thread loads 32 channels x float4 (coalesced 16B/lane, FULL unroll ->
// 32 loads in flight), LDS-reduces 8-way across subgroups.
// ---------------------------------------------------------------------------
__global__ __launch_bounds__(256) void reduce_kernel(
    const float* __restrict__ x,
    float* __restrict__ avg_map,
    float* __restrict__ max_map)
{
    const int n   = blockIdx.y;
    const int tid = threadIdx.x;
    const int sub = tid >> 5;       // 0..7 channel subgroup
    const int pos = tid & 31;       // 0..31 position within chunk
    const int p4  = blockIdx.x * 32 + pos;   // float4 index within image
    const bool active = (p4 < HW4);

    float4 s = make_float4(0.f, 0.f, 0.f, 0.f);
    float4 m = make_float4(-INFINITY, -INFINITY, -INFINITY, -INFINITY);

    if (active) {
        const float* px = x + (size_t)n * CHW + (size_t)(sub * 32) * HW + (size_t)p4 * 4;
        #pragma unroll
        for (int i = 0; i < 32; ++i) {
            float4 v = *reinterpret_cast<const float4*>(px + (size_t)i * HW);
            s.x += v.x; s.y += v.y; s.z += v.z; s.w += v.w;
            m.x = fmaxf(m.x, v.x); m.y = fmaxf(m.y, v.y);
            m.z = fmaxf(m.z, v.z); m.w = fmaxf(m.w, v.w);
        }
    }

    __shared__ float4 ssum[256];
    __shared__ float4 smax[256];
    ssum[tid] = s;
    smax[tid] = m;
    __syncthreads();

    if (tid < 32) {
        const int myp4 = blockIdx.x * 32 + tid;
        if (myp4 < HW4) {
            float4 a = ssum[tid];
            #pragma unroll
            for (int k = 1; k < 8; ++k) {
                float4 v = ssum[tid + k * 32];
                a.x += v.x; a.y += v.y; a.z += v.z; a.w += v.w;
            }
            const float inv = 1.0f / 256.0f;
            a.x *= inv; a.y *= inv; a.z *= inv; a.w *= inv;
            *reinterpret_cast<float4*>(avg_map + (size_t)n * HW + (size_t)myp4 * 4) = a;
        }
    } else if (tid < 64) {
        const int p = tid - 32;
        const int myp4 = blockIdx.x * 32 + p;
        if (myp4 < HW4) {
            float4 a = smax[p];
            #pragma unroll
            for (int k = 1; k < 8; ++k) {
                float4 v = smax[p + k * 32];
                a.x = fmaxf(a.x, v.x); a.y = fmaxf(a.y, v.y);
                a.z = fmaxf(a.z, v.z); a.w = fmaxf(a.w, v.w);
            }
            *reinterpret_cast<float4*>(max_map + (size_t)n * HW + (size_t)myp4 * 4) = a;
        }
    }
}

// ---------------------------------------------------------------------------
// Kernel B (fused): 7x7 conv + bias + sigmoid on [avg;max], then
// out = x * scale, one block per (image, row). Grid (56, 32) = 1792 blocks
// -> 7 blocks/CU, 28 waves/CU: full-machine occupancy for the BW-bound apply.
// LDS: 2ch x 7 rows x 62 cols zero-padded halo (zero pad == conv zero pad).
// ---------------------------------------------------------------------------
#define LDSW 62   // 56 + 3 pad each side
__global__ __launch_bounds__(256) void conv_apply_kernel(
    const float* __restrict__ x,
    const float* __restrict__ avg_map,
    const float* __restrict__ max_map,
    const float* __restrict__ w,   // [1][2][7][7] OIHW
    const float* __restrict__ b,   // [1]
    float* __restrict__ out)
{
    const int n   = blockIdx.y;
    const int row = blockIdx.x;          // output row 0..55
    const int tid = threadIdx.x;

    __shared__ float s_in[2][7][LDSW];
    __shared__ float s_w[98];
    __shared__ float s_b;
    __shared__ float s_scale[W];         // 56 scales for this row

    float* s_raw = &s_in[0][0][0];
    #pragma unroll
    for (int e = tid; e < 2 * 7 * LDSW; e += 256) s_raw[e] = 0.0f;
    if (tid < 98) s_w[tid] = w[tid];
    if (tid == 0) s_b = b[0];
    __syncthreads();

    // stage 7-row halo of both maps (zero outside image)
    for (int e = tid; e < 2 * 7 * W; e += 256) {
        const int ch  = e / (7 * W);
        const int r   = (e / W) % 7;
        const int col = e % W;
        const int gr  = row - 3 + r;
        if (gr >= 0 && gr < H) {
            const float* src = (ch == 0) ? avg_map : max_map;
            s_in[ch][r][col + 3] = src[(size_t)n * HW + gr * W + col];
        }
    }
    __syncthreads();

    // conv + sigmoid for this row (threads 0..55)
    if (tid < W) {
        float acc = s_b;
        #pragma unroll
        for (int ch = 0; ch < 2; ++ch)
            #pragma unroll
            for (int i = 0; i < 7; ++i)
                #pragma unroll
                for (int j = 0; j < 7; ++j)
                    acc = fmaf(s_in[ch][i][tid + j], s_w[ch * 49 + i * 7 + j], acc);
        s_scale[tid] = 1.0f / (1.0f + expf(-acc));
    }
    __syncthreads();

    // apply: 256 channels x 14 float4 per row = 3584 float4 = 14 iters/thread
    const float* xrow = x + (size_t)n * CHW + (size_t)row * W;
    float*       orow = out + (size_t)n * CHW + (size_t)row * W;
    #pragma unroll
    for (int iter = 0; iter < 14; ++iter) {
        const int e  = iter * 256 + tid;
        const int c  = e / W4;           // channel 0..255
        const int w4 = e - c * W4;       // float4 col 0..13
        const size_t off = (size_t)c * HW + (size_t)w4 * 4;
        float4 v = *reinterpret_cast<const float4*>(xrow + off);
        v.x *= s_scale[w4 * 4 + 0];
        v.y *= s_scale[w4 * 4 + 1];
        v.z *= s_scale[w4 * 4 + 2];
        v.w *= s_scale[w4 * 4 + 3];
        *reinterpret_cast<float4*>(orow + off) = v;
    }
}

extern "C" void kernel_launch(void* const* d_in, const int* in_sizes, int n_in,
                              void* d_out, int out_size, void* d_ws, size_t ws_size,
                              hipStream_t stream)
{
    const float* x = (const float*)d_in[0];   // 25,690,112 floats
    const float* w = (const float*)d_in[1];   // 98 floats (1,2,7,7)
    const float* b = (const float*)d_in[2];   // 1 float
    float* out = (float*)d_out;

    float* ws      = (float*)d_ws;
    float* avg_map = ws;                        // 100,352 floats
    float* max_map = ws + (size_t)N_IMG * HW;   // 100,352 floats

    dim3 gA((HW4 + 31) / 32, N_IMG);   // (25, 32)
    reduce_kernel<<<gA, 256, 0, stream>>>(x, avg_map, max_map);

    dim3 gB(H, N_IMG);                 // (56, 32)
    conv_apply_kernel<<<gB, 256, 0, stream>>>(x, avg_map, max_map, w, b, out);
}

// Round 11
// 213.205 us; speedup vs baseline: 1.0452x; 1.0452x over previous
//
#include <hip/hip_runtime.h>
#include <math.h>

#define N_IMG 32
#define C_CH  256
#define H     56
#define W     56
#define HW    (H * W)          // 3136
#define CHW   (C_CH * HW)      // 802816
#define HW4   (HW / 4)         // 784
#define W4    (W / 4)          // 14

typedef float vfloat4 __attribute__((ext_vector_type(4)));  // clang-native, ok for nontemporal builtins

// ---------------------------------------------------------------------------
// Kernel A: per-(n,h,w) channel mean and max over C=256.
// Block = 256 threads: 8 channel-subgroups x 32 float4-positions.
// Each thread loads 32 channels x float4 (coalesced, 512B-aligned runs,
// full unroll -> 32 loads in flight), LDS-reduces 8-way across subgroups.
// Normal (caching) loads: x must stay L3-resident for the apply re-read.
// ---------------------------------------------------------------------------
__global__ __launch_bounds__(256) void reduce_kernel(
    const float* __restrict__ x,
    float* __restrict__ avg_map,
    float* __restrict__ max_map)
{
    const int n   = blockIdx.y;
    const int tid = threadIdx.x;
    const int sub = tid >> 5;       // 0..7 channel subgroup
    const int pos = tid & 31;       // 0..31 position within chunk
    const int p4  = blockIdx.x * 32 + pos;   // float4 index within image
    const bool active = (p4 < HW4);

    float4 s = make_float4(0.f, 0.f, 0.f, 0.f);
    float4 m = make_float4(-INFINITY, -INFINITY, -INFINITY, -INFINITY);

    if (active) {
        const float* px = x + (size_t)n * CHW + (size_t)(sub * 32) * HW + (size_t)p4 * 4;
        #pragma unroll
        for (int i = 0; i < 32; ++i) {
            float4 v = *reinterpret_cast<const float4*>(px + (size_t)i * HW);
            s.x += v.x; s.y += v.y; s.z += v.z; s.w += v.w;
            m.x = fmaxf(m.x, v.x); m.y = fmaxf(m.y, v.y);
            m.z = fmaxf(m.z, v.z); m.w = fmaxf(m.w, v.w);
        }
    }

    __shared__ float4 ssum[256];
    __shared__ float4 smax[256];
    ssum[tid] = s;
    smax[tid] = m;
    __syncthreads();

    if (tid < 32) {
        const int myp4 = blockIdx.x * 32 + tid;
        if (myp4 < HW4) {
            float4 a = ssum[tid];
            #pragma unroll
            for (int k = 1; k < 8; ++k) {
                float4 v = ssum[tid + k * 32];
                a.x += v.x; a.y += v.y; a.z += v.z; a.w += v.w;
            }
            const float inv = 1.0f / 256.0f;
            a.x *= inv; a.y *= inv; a.z *= inv; a.w *= inv;
            *reinterpret_cast<float4*>(avg_map + (size_t)n * HW + (size_t)myp4 * 4) = a;
        }
    } else if (tid < 64) {
        const int p = tid - 32;
        const int myp4 = blockIdx.x * 32 + p;
        if (myp4 < HW4) {
            float4 a = smax[p];
            #pragma unroll
            for (int k = 1; k < 8; ++k) {
                float4 v = smax[p + k * 32];
                a.x = fmaxf(a.x, v.x); a.y = fmaxf(a.y, v.y);
                a.z = fmaxf(a.z, v.z); a.w = fmaxf(a.w, v.w);
            }
            *reinterpret_cast<float4*>(max_map + (size_t)n * HW + (size_t)myp4 * 4) = a;
        }
    }
}

// ---------------------------------------------------------------------------
// Kernel B (fused): 7x7 conv + bias + sigmoid on [avg;max], then
// out = x * scale, one block per (image, row). Grid (56, 32) = 1792 blocks
// -> 7 blocks/CU, 28 waves/CU.
// out is written with __builtin_nontemporal_store (nt flag) so the 103 MB of
// output write-allocations don't evict x from L3 (x re-read should hit).
// ---------------------------------------------------------------------------
#define LDSW 62   // 56 + 3 pad each side
__global__ __launch_bounds__(256) void conv_apply_kernel(
    const float* __restrict__ x,
    const float* __restrict__ avg_map,
    const float* __restrict__ max_map,
    const float* __restrict__ w,   // [1][2][7][7] OIHW
    const float* __restrict__ b,   // [1]
    float* __restrict__ out)
{
    const int n   = blockIdx.y;
    const int row = blockIdx.x;          // output row 0..55
    const int tid = threadIdx.x;

    __shared__ float s_in[2][7][LDSW];
    __shared__ float s_w[98];
    __shared__ float s_b;
    __shared__ float s_scale[W];         // 56 scales for this row

    float* s_raw = &s_in[0][0][0];
    #pragma unroll
    for (int e = tid; e < 2 * 7 * LDSW; e += 256) s_raw[e] = 0.0f;
    if (tid < 98) s_w[tid] = w[tid];
    if (tid == 0) s_b = b[0];
    __syncthreads();

    // stage 7-row halo of both maps (zero outside image)
    for (int e = tid; e < 2 * 7 * W; e += 256) {
        const int ch  = e / (7 * W);
        const int r   = (e / W) % 7;
        const int col = e % W;
        const int gr  = row - 3 + r;
        if (gr >= 0 && gr < H) {
            const float* src = (ch == 0) ? avg_map : max_map;
            s_in[ch][r][col + 3] = src[(size_t)n * HW + gr * W + col];
        }
    }
    __syncthreads();

    // conv + sigmoid for this row (threads 0..55)
    if (tid < W) {
        float acc = s_b;
        #pragma unroll
        for (int ch = 0; ch < 2; ++ch)
            #pragma unroll
            for (int i = 0; i < 7; ++i)
                #pragma unroll
                for (int j = 0; j < 7; ++j)
                    acc = fmaf(s_in[ch][i][tid + j], s_w[ch * 49 + i * 7 + j], acc);
        s_scale[tid] = 1.0f / (1.0f + expf(-acc));
    }
    __syncthreads();

    // apply: 256 channels x 14 float4 per row = 3584 float4 = 14 iters/thread
    const float* xrow = x + (size_t)n * CHW + (size_t)row * W;
    float*       orow = out + (size_t)n * CHW + (size_t)row * W;
    #pragma unroll
    for (int iter = 0; iter < 14; ++iter) {
        const int e  = iter * 256 + tid;
        const int c  = e / W4;           // channel 0..255
        const int w4 = e - c * W4;       // float4 col 0..13
        const size_t off = (size_t)c * HW + (size_t)w4 * 4;
        float4 v = *reinterpret_cast<const float4*>(xrow + off);
        vfloat4 nv;
        nv.x = v.x * s_scale[w4 * 4 + 0];
        nv.y = v.y * s_scale[w4 * 4 + 1];
        nv.z = v.z * s_scale[w4 * 4 + 2];
        nv.w = v.w * s_scale[w4 * 4 + 3];
        __builtin_nontemporal_store(nv, reinterpret_cast<vfloat4*>(orow + off));
    }
}

extern "C" void kernel_launch(void* const* d_in, const int* in_sizes, int n_in,
                              void* d_out, int out_size, void* d_ws, size_t ws_size,
                              hipStream_t stream)
{
    const float* x = (const float*)d_in[0];   // 25,690,112 floats
    const float* w = (const float*)d_in[1];   // 98 floats (1,2,7,7)
    const float* b = (const float*)d_in[2];   // 1 float
    float* out = (float*)d_out;

    float* ws      = (float*)d_ws;
    float* avg_map = ws;                        // 100,352 floats
    float* max_map = ws + (size_t)N_IMG * HW;   // 100,352 floats

    dim3 gA((HW4 + 31) / 32, N_IMG);   // (25, 32)
    reduce_kernel<<<gA, 256, 0, stream>>>(x, avg_map, max_map);

    dim3 gB(H, N_IMG);                 // (56, 32)
    conv_apply_kernel<<<gB, 256, 0, stream>>>(x, avg_map, max_map, w, b, out);
}